// Round 1
// baseline (963.776 us; speedup 1.0000x reference)
//
#include <hip/hip_runtime.h>
#include <cstdint>

#define Bc 256
#define Cc 64
#define Hc 128
#define Oc 64
#define Tc 512

typedef short bf16x8 __attribute__((ext_vector_type(8)));
typedef float f32x4 __attribute__((ext_vector_type(4)));
typedef _Float16 f16x8 __attribute__((ext_vector_type(8)));
typedef _Float16 h4 __attribute__((ext_vector_type(4)));

static __device__ __forceinline__ unsigned short f2b(float f) {
  unsigned u = __float_as_uint(f);
  unsigned r = u + 0x7FFFu + ((u >> 16) & 1u);   // RNE
  return (unsigned short)(r >> 16);
}

static __device__ __forceinline__ float sigf(float x) {
  return 1.f / (1.f + __expf(-x));   // overflow-safe: exp->inf -> 0
}

// ---------------------------------------------------------------------------
// K0: weight prep.
//  wdgT [192][64] bf16, w2T [384][128] bf16, hyT [64][128] bf16 (as before)
//  whT  [3][128][128] fp16: [g][j][k] = w_h*[k][j]   (B-fragment layout)
// ---------------------------------------------------------------------------
__global__ __launch_bounds__(256) void k_wprep(
    const float* __restrict__ w_dg_x, const float* __restrict__ w_dg_h,
    const float* __restrict__ w_xz, const float* __restrict__ w_mz,
    const float* __restrict__ w_xr, const float* __restrict__ w_mr,
    const float* __restrict__ w_xh, const float* __restrict__ w_mh,
    const float* __restrict__ w_hy,
    const float* __restrict__ w_hz, const float* __restrict__ w_hr,
    const float* __restrict__ w_hh,
    unsigned short* __restrict__ wdgT, unsigned short* __restrict__ w2T,
    unsigned short* __restrict__ hyT, _Float16* __restrict__ whT) {
  int e = blockIdx.x * 256 + threadIdx.x;
  if (e < 12288) {                       // wdgT: 192 x 64
    int n = e >> 6, k = e & 63;
    float v = (n < 64) ? w_dg_x[k * Cc + n] : w_dg_h[k * Hc + (n - 64)];
    wdgT[e] = f2b(v);
  } else if (e < 61440) {                // w2T: 384 x 128
    int i = e - 12288;
    int n = i >> 7, k = i & 127;
    int gate = n >> 7, nc = n & 127;
    const float* wx = (gate == 0) ? w_xz : (gate == 1) ? w_xr : w_xh;
    const float* wm = (gate == 0) ? w_mz : (gate == 1) ? w_mr : w_mh;
    float v = (k < 64) ? wx[k * Hc + nc] : wm[(k - 64) * Hc + nc];
    w2T[i] = f2b(v);
  } else if (e < 69632) {                // hyT: 64 x 128
    int i = e - 61440;
    int n = i >> 7, k = i & 127;
    hyT[i] = f2b(w_hy[k * Oc + n]);
  } else if (e < 118784) {               // whT: 3 x 128 x 128 fp16, [g][j][k]
    int i = e - 69632;
    int g = i >> 14, rem = i & 16383;
    int j = rem >> 7, k = rem & 127;
    const float* wh_ = (g == 0) ? w_hz : (g == 1) ? w_hr : w_hh;
    whT[i] = (_Float16)wh_[k * Hc + j];
  }
}

// ---------------------------------------------------------------------------
// K1: segmented x_last select-scan (unchanged).
// ---------------------------------------------------------------------------
__global__ __launch_bounds__(256) void k_scan(const float* __restrict__ input,
                                              const float* __restrict__ lastx,
                                              float* __restrict__ xlast) {
  const int b = blockIdx.x;
  const int seg = threadIdx.x >> 6;
  const int c = threadIdx.x & 63;
  const int tb = seg * 128;
  __shared__ float segval[4][64];
  __shared__ int   segvld[4][64];
  __shared__ float segcin[4][64];
  const float* xp = input + ((size_t)(b * 3 + 0) * Cc + c) * Tc;
  const float* mp = input + ((size_t)(b * 3 + 1) * Cc + c) * Tc;

  float val = 0.f; int vld = 0;
  for (int t = tb + 127; t >= tb; --t) {
    if (mp[t] > 0.f) { val = xp[t]; vld = 1; break; }
  }
  segval[seg][c] = val; segvld[seg][c] = vld;
  __syncthreads();
  if (threadIdx.x < 64) {
    float carry = lastx[b * Cc + threadIdx.x];
    #pragma unroll
    for (int s = 0; s < 4; ++s) {
      segcin[s][threadIdx.x] = carry;
      if (segvld[s][threadIdx.x]) carry = segval[s][threadIdx.x];
    }
  }
  __syncthreads();
  float cur = segcin[seg][c];
  float* op = xlast + ((size_t)b * Tc + tb) * Cc + c;
  for (int t = 0; t < 128; t += 4) {
    const float4 m4 = *reinterpret_cast<const float4*>(mp + tb + t);
    const float4 x4 = *reinterpret_cast<const float4*>(xp + tb + t);
    cur = (m4.x > 0.f) ? x4.x : cur; op[(size_t)(t + 0) * Cc] = cur;
    cur = (m4.y > 0.f) ? x4.y : cur; op[(size_t)(t + 1) * Cc] = cur;
    cur = (m4.z > 0.f) ? x4.z : cur; op[(size_t)(t + 2) * Cc] = cur;
    cur = (m4.w > 0.f) ? x4.w : cur; op[(size_t)(t + 3) * Cc] = cur;
  }
}

// ---------------------------------------------------------------------------
// K2: MFMA bf16 pre-compute. Output now packed [t][b][H][4] fp16:
//  s=0 gamma_h, s=1 pre_z, s=2 pre_r, s=3 pre_h  (one dwordx2 per (b,col) in k_seq)
// ---------------------------------------------------------------------------
__global__ __launch_bounds__(256) void k_pre(
    const float* __restrict__ input, const float* __restrict__ x_mean,
    const float* __restrict__ xlast,
    const float* __restrict__ b_dg_x, const float* __restrict__ b_dg_h,
    const float* __restrict__ b_mz, const float* __restrict__ b_mh,
    const unsigned short* __restrict__ wdgT, const unsigned short* __restrict__ w2T,
    _Float16* __restrict__ P4) {
  __shared__ unsigned short d16[64 * 72];
  __shared__ unsigned short A16[64 * 136];
  __shared__ float x_cs[64 * 68];
  __shared__ float m_cs[64 * 68];

  const int tid = threadIdx.x;
  const int b = blockIdx.x >> 3;
  const int t0 = (blockIdx.x & 7) * 64;
  const int w = tid >> 6, lane = tid & 63, quad = lane >> 4, l16 = lane & 15;

  #pragma unroll
  for (int i = 0; i < 4; ++i) {
    int e = tid + i * 256;
    int c = e >> 4, t4 = (e & 15) * 4;
    const size_t rx = ((size_t)(b * 3 + 0) * Cc + c) * Tc + t0 + t4;
    const size_t rm = ((size_t)(b * 3 + 1) * Cc + c) * Tc + t0 + t4;
    const size_t rd = ((size_t)(b * 3 + 2) * Cc + c) * Tc + t0 + t4;
    float4 xv = *reinterpret_cast<const float4*>(input + rx);
    float4 mv = *reinterpret_cast<const float4*>(input + rm);
    float4 dv = *reinterpret_cast<const float4*>(input + rd);
    *reinterpret_cast<float4*>(&x_cs[c * 68 + t4]) = xv;
    *reinterpret_cast<float4*>(&m_cs[c * 68 + t4]) = mv;
    A16[(t4 + 0) * 136 + 64 + c] = f2b(mv.x);
    A16[(t4 + 1) * 136 + 64 + c] = f2b(mv.y);
    A16[(t4 + 2) * 136 + 64 + c] = f2b(mv.z);
    A16[(t4 + 3) * 136 + 64 + c] = f2b(mv.w);
    d16[(t4 + 0) * 72 + c] = f2b(dv.x);
    d16[(t4 + 1) * 72 + c] = f2b(dv.y);
    d16[(t4 + 2) * 72 + c] = f2b(dv.z);
    d16[(t4 + 3) * 72 + c] = f2b(dv.w);
  }
  __syncthreads();

  f32x4 accA[4][3];
  #pragma unroll
  for (int mt = 0; mt < 4; ++mt)
    #pragma unroll
    for (int j = 0; j < 3; ++j) accA[mt][j] = {0.f, 0.f, 0.f, 0.f};
  #pragma unroll
  for (int kt = 0; kt < 2; ++kt) {
    bf16x8 a[4];
    #pragma unroll
    for (int mt = 0; mt < 4; ++mt)
      a[mt] = *reinterpret_cast<const bf16x8*>(&d16[(mt * 16 + l16) * 72 + kt * 32 + quad * 8]);
    #pragma unroll
    for (int j = 0; j < 3; ++j) {
      int nt = w + j * 4;
      bf16x8 bb = *reinterpret_cast<const bf16x8*>(wdgT + (nt * 16 + l16) * 64 + kt * 32 + quad * 8);
      #pragma unroll
      for (int mt = 0; mt < 4; ++mt)
        accA[mt][j] = __builtin_amdgcn_mfma_f32_16x16x32_bf16(a[mt], bb, accA[mt][j], 0, 0, 0);
    }
  }

  {
    int c = w * 16 + l16;
    float xmn = x_mean[b * Cc + c];
    float bx = b_dg_x[c];
    #pragma unroll
    for (int mt = 0; mt < 4; ++mt)
      #pragma unroll
      for (int r = 0; r < 4; ++r) {
        int row = mt * 16 + quad * 4 + r;
        float g = __expf(-fmaxf(accA[mt][0][r] + bx, 0.f));
        float mv = m_cs[c * 68 + row], xv = x_cs[c * 68 + row];
        float xl = xlast[((size_t)b * Tc + t0 + row) * Cc + c];
        float xin = mv * xv + (1.f - mv) * (g * xl + (1.f - g) * xmn);
        A16[row * 136 + c] = f2b(xin);
      }
  }
  #pragma unroll
  for (int j = 1; j < 3; ++j) {
    int nh = (w + j * 4) * 16 - 64 + l16;
    float bh = b_dg_h[nh];
    #pragma unroll
    for (int mt = 0; mt < 4; ++mt)
      #pragma unroll
      for (int r = 0; r < 4; ++r) {
        int row = mt * 16 + quad * 4 + r;
        P4[(((size_t)(t0 + row) * Bc + b) * Hc + nh) * 4 + 0] =
            (_Float16)__expf(-fmaxf(accA[mt][j][r] + bh, 0.f));
      }
  }
  __syncthreads();

  f32x4 accB[4][6];
  #pragma unroll
  for (int mt = 0; mt < 4; ++mt)
    #pragma unroll
    for (int j = 0; j < 6; ++j) accB[mt][j] = {0.f, 0.f, 0.f, 0.f};
  #pragma unroll
  for (int kt = 0; kt < 4; ++kt) {
    bf16x8 a[4];
    #pragma unroll
    for (int mt = 0; mt < 4; ++mt)
      a[mt] = *reinterpret_cast<const bf16x8*>(&A16[(mt * 16 + l16) * 136 + kt * 32 + quad * 8]);
    #pragma unroll
    for (int j = 0; j < 6; ++j) {
      int nt = (j >> 1) * 8 + w + (j & 1) * 4;
      bf16x8 bb = *reinterpret_cast<const bf16x8*>(w2T + (nt * 16 + l16) * 128 + kt * 32 + quad * 8);
      #pragma unroll
      for (int mt = 0; mt < 4; ++mt)
        accB[mt][j] = __builtin_amdgcn_mfma_f32_16x16x32_bf16(a[mt], bb, accB[mt][j], 0, 0, 0);
    }
  }
  #pragma unroll
  for (int j = 0; j < 6; ++j) {
    int nt = (j >> 1) * 8 + w + (j & 1) * 4;
    int gate = nt >> 3;
    int col = (nt & 7) * 16 + l16;
    float bias = (gate == 0) ? b_mz[col] : (gate == 2) ? b_mh[col] : 0.f;
    #pragma unroll
    for (int mt = 0; mt < 4; ++mt)
      #pragma unroll
      for (int r = 0; r < 4; ++r) {
        int row = mt * 16 + quad * 4 + r;
        P4[(((size_t)(t0 + row) * Bc + b) * Hc + col) * 4 + gate + 1] =
            (_Float16)(accB[mt][j][r] + bias);
      }
  }
}

// ---------------------------------------------------------------------------
// K3: sequential h-recurrence, batched 16-wide onto the matrix pipe.
// grid = 16 blocks, 512 threads = 8 waves. Block owns batches b0..b0+15.
// Wave w owns output cols [w*16, w*16+16) for z, r AND h~ (so the gate
// combine is wave-local in the MFMA C-layout: row=batch=quad*4+ri, col=l16).
// Weights live in 48 VGPRs/wave. Per step: 2 barriers, 12 MFMA/wave.
// hd and r*hd round-trip through LDS fp16 tiles [16][136] (A-frag layout,
// padded stride => ~2-way banks, same pattern as k_pre's verified A16).
// ---------------------------------------------------------------------------
__global__ __launch_bounds__(512, 2) void k_seq(
    const _Float16* __restrict__ P4,    // [T][B][H][4] fp16 {gamma,pz,pr,ph}
    const _Float16* __restrict__ whT,   // [3][128][128] fp16 [j][k]
    float* __restrict__ hs_out) {
  const int tid = threadIdx.x;
  const int w = tid >> 6, lane = tid & 63, quad = lane >> 4, l16 = lane & 15;
  const int b0 = blockIdx.x * 16;
  const int col = w * 16 + l16;

  __shared__ _Float16 hA[16 * 136];
  __shared__ _Float16 rA[16 * 136];

  // B-fragments: lane(l16)=col, quad=k-octet, kt walks K=128.
  f16x8 bz[4], br[4], bh[4];
  #pragma unroll
  for (int kt = 0; kt < 4; ++kt) {
    int off = col * 128 + kt * 32 + quad * 8;
    bz[kt] = *reinterpret_cast<const f16x8*>(whT + off);
    br[kt] = *reinterpret_cast<const f16x8*>(whT + 16384 + off);
    bh[kt] = *reinterpret_cast<const f16x8*>(whT + 32768 + off);
  }

  for (int i = tid; i < 16 * 136; i += 512) hA[i] = (_Float16)0.f;

  const size_t strideT = (size_t)Bc * Hc * 4;
  const _Float16* pbase = P4 + ((size_t)(b0 + quad * 4) * Hc + col) * 4;

  float pz[4], pr[4], ph[4], hd[4], zs[4];
  #pragma unroll
  for (int ri = 0; ri < 4; ++ri) {
    h4 s = *reinterpret_cast<const h4*>(pbase + (size_t)ri * (Hc * 4));
    pz[ri] = (float)s[1]; pr[ri] = (float)s[2]; ph[ri] = (float)s[3];
    hd[ri] = 0.f;
  }

  for (int t = 0; t < Tc; ++t) {
    __syncthreads();                       // barrier A: hA(t) ready
    // prefetch next-step streams (consumed at end of this iteration)
    int tn = (t + 1 < Tc) ? t + 1 : t;
    h4 sn[4];
    #pragma unroll
    for (int ri = 0; ri < 4; ++ri)
      sn[ri] = *reinterpret_cast<const h4*>(pbase + (size_t)tn * strideT +
                                            (size_t)ri * (Hc * 4));

    // GEMM1: z,r partial = hd @ {w_hz,w_hr}; acc seeded with precomputed sums
    f32x4 accz = {pz[0], pz[1], pz[2], pz[3]};
    f32x4 accr = {pr[0], pr[1], pr[2], pr[3]};
    #pragma unroll
    for (int kt = 0; kt < 4; ++kt) {
      f16x8 a = *reinterpret_cast<const f16x8*>(&hA[l16 * 136 + kt * 32 + quad * 8]);
      accz = __builtin_amdgcn_mfma_f32_16x16x32_f16(a, bz[kt], accz, 0, 0, 0);
      accr = __builtin_amdgcn_mfma_f32_16x16x32_f16(a, br[kt], accr, 0, 0, 0);
    }
    #pragma unroll
    for (int ri = 0; ri < 4; ++ri) {
      float z = sigf(accz[ri]);
      float r = sigf(accr[ri]);
      zs[ri] = z;
      rA[(quad * 4 + ri) * 136 + col] = (_Float16)(r * hd[ri]);
    }
    __syncthreads();                       // barrier B: rA ready (hA reads done)

    // GEMM2: h~ = rhd @ w_hh, seeded with pre_h
    f32x4 acch = {ph[0], ph[1], ph[2], ph[3]};
    #pragma unroll
    for (int kt = 0; kt < 4; ++kt) {
      f16x8 a = *reinterpret_cast<const f16x8*>(&rA[l16 * 136 + kt * 32 + quad * 8]);
      acch = __builtin_amdgcn_mfma_f32_16x16x32_f16(a, bh[kt], acch, 0, 0, 0);
    }
    #pragma unroll
    for (int ri = 0; ri < 4; ++ri) {
      float e2 = __expf(2.f * acch[ri]);
      float ht = 1.f - 2.f / (e2 + 1.f);   // overflow-safe tanh
      float hn = (1.f - zs[ri]) * hd[ri] + zs[ri] * ht;
      hs_out[((size_t)(b0 + quad * 4 + ri) * Tc + t) * Hc + col] = hn;
      float gn = (float)sn[ri][0];
      hd[ri] = gn * hn;                    // hd for step t+1
      hA[(quad * 4 + ri) * 136 + col] = (_Float16)hd[ri];
      pz[ri] = (float)sn[ri][1]; pr[ri] = (float)sn[ri][2]; ph[ri] = (float)sn[ri][3];
    }
  }
}

// ---------------------------------------------------------------------------
// K4: ys = sigmoid(hs @ w_hy + b_hy) via MFMA bf16 (unchanged).
// ---------------------------------------------------------------------------
__global__ __launch_bounds__(256) void k_y(const float* __restrict__ hs,
                                           const unsigned short* __restrict__ hyT,
                                           const float* __restrict__ b_hy,
                                           float* __restrict__ ys) {
  __shared__ unsigned short A16[64 * 136];
  const int tid = threadIdx.x;
  const int r0 = blockIdx.x * 64;
  const int w = tid >> 6, lane = tid & 63, quad = lane >> 4, l16 = lane & 15;

  #pragma unroll
  for (int i = 0; i < 8; ++i) {
    int e = tid + i * 256;
    int row = e >> 5, k4 = (e & 31) * 4;
    float4 hv = *reinterpret_cast<const float4*>(&hs[(size_t)(r0 + row) * Hc + k4]);
    unsigned short s0 = f2b(hv.x), s1 = f2b(hv.y), s2 = f2b(hv.z), s3 = f2b(hv.w);
    unsigned int lo = (unsigned int)s0 | ((unsigned int)s1 << 16);
    unsigned int hi = (unsigned int)s2 | ((unsigned int)s3 << 16);
    *reinterpret_cast<uint2*>(&A16[row * 136 + k4]) = make_uint2(lo, hi);
  }
  __syncthreads();

  f32x4 acc[4];
  #pragma unroll
  for (int mt = 0; mt < 4; ++mt) acc[mt] = {0.f, 0.f, 0.f, 0.f};
  #pragma unroll
  for (int kt = 0; kt < 4; ++kt) {
    bf16x8 bb = *reinterpret_cast<const bf16x8*>(hyT + (w * 16 + l16) * 128 + kt * 32 + quad * 8);
    #pragma unroll
    for (int mt = 0; mt < 4; ++mt) {
      bf16x8 a = *reinterpret_cast<const bf16x8*>(&A16[(mt * 16 + l16) * 136 + kt * 32 + quad * 8]);
      acc[mt] = __builtin_amdgcn_mfma_f32_16x16x32_bf16(a, bb, acc[mt], 0, 0, 0);
    }
  }
  int col = w * 16 + l16;
  float bias = b_hy[col];
  #pragma unroll
  for (int mt = 0; mt < 4; ++mt)
    #pragma unroll
    for (int r = 0; r < 4; ++r) {
      int row = mt * 16 + quad * 4 + r;
      ys[(size_t)(r0 + row) * Oc + col] = 1.f / (1.f + __expf(-(acc[mt][r] + bias)));
    }
}

// ---------------------------------------------------------------------------
extern "C" void kernel_launch(void* const* d_in, const int* in_sizes, int n_in,
                              void* d_out, int out_size, void* d_ws, size_t ws_size,
                              hipStream_t stream) {
  const float* input  = (const float*)d_in[0];
  const float* x_mean = (const float*)d_in[1];
  const float* lastx  = (const float*)d_in[2];
  const float* w_dg_x = (const float*)d_in[3];
  const float* b_dg_x = (const float*)d_in[4];
  const float* w_dg_h = (const float*)d_in[5];
  const float* b_dg_h = (const float*)d_in[6];
  const float* w_xz   = (const float*)d_in[7];
  const float* w_hz   = (const float*)d_in[8];
  const float* w_mz   = (const float*)d_in[9];
  const float* b_mz   = (const float*)d_in[10];
  const float* w_xr   = (const float*)d_in[11];
  const float* w_hr   = (const float*)d_in[12];
  const float* w_mr   = (const float*)d_in[13];
  const float* w_xh   = (const float*)d_in[14];
  const float* w_hh   = (const float*)d_in[15];
  const float* w_mh   = (const float*)d_in[16];
  const float* b_mh   = (const float*)d_in[17];
  const float* w_hy   = (const float*)d_in[18];
  const float* b_hy   = (const float*)d_in[19];

  float* ys = (float*)d_out;                          // (B,T,O)
  float* hs = (float*)d_out + (size_t)Bc * Tc * Oc;   // (B,T,H)

  const size_t BTC = (size_t)Bc * Tc * Cc;            // 8,388,608
  const size_t BTH = (size_t)Bc * Tc * Hc;            // 16,777,216

  float* xlast = (float*)d_ws;
  _Float16* P4 = (_Float16*)(xlast + BTC);            // [T][B][H][4] fp16
  unsigned short* wdgT = (unsigned short*)(P4 + BTH * 4);
  unsigned short* w2T  = wdgT + 192 * 64;
  unsigned short* hyT  = w2T + 384 * 128;
  _Float16* whT16 = (_Float16*)(hyT + 64 * 128);      // 3*128*128 fp16

  k_wprep<<<464, 256, 0, stream>>>(w_dg_x, w_dg_h, w_xz, w_mz, w_xr, w_mr,
                                   w_xh, w_mh, w_hy, w_hz, w_hr, w_hh,
                                   wdgT, w2T, hyT, whT16);
  k_scan<<<Bc, 256, 0, stream>>>(input, lastx, xlast);
  k_pre<<<(Bc * Tc) / 64, 256, 0, stream>>>(input, x_mean, xlast,
                                            b_dg_x, b_dg_h, b_mz, b_mh,
                                            wdgT, w2T, P4);
  k_seq<<<Bc / 16, 512, 0, stream>>>(P4, whT16, hs);
  k_y<<<(Bc * Tc) / 64, 256, 0, stream>>>(hs, hyT, b_hy, ys);
}